// Round 14
// baseline (378.230 us; speedup 1.0000x reference)
//
#include <hip/hip_runtime.h>

#define NNODES 100000
#define NEDGES 625000
#define DFEAT  128
#define NGRAPH 256
#define DOUTC  10
#define NSL    8                         // feature slices (one per XCD)
#define SLF    16                        // feats per slice (32 B)

typedef __attribute__((ext_vector_type(8))) short bf16x8;
typedef __attribute__((ext_vector_type(4))) float f32x4;
typedef __attribute__((ext_vector_type(8))) ushort ushort8v;

#define SL ((size_t)NNODES * SLF)        // ushorts per slice plane

__device__ __forceinline__ ushort f2bf(float f) {
    __bf16 b = (__bf16)f;
    return __builtin_bit_cast(ushort, b);
}
__device__ __forceinline__ float bf2f(ushort u) {
    return __builtin_bit_cast(float, (uint)u << 16);
}

// ---------------------------------------------------------------------------
// convert_all: weights->bf16, x->bf16 (SLICED layout), zero gsum/deg/counter
// H layout: Hsl[slice][node][16feats]; group g of row n -> slice g>>1, half g&1
// ---------------------------------------------------------------------------
__global__ __launch_bounds__(256) void convert_all(const float* __restrict__ x,
                                                   const float* __restrict__ w0,
                                                   const float* __restrict__ w1,
                                                   const float* __restrict__ w2,
                                                   const float* __restrict__ w3,
                                                   const float* __restrict__ w4,
                                                   const float* __restrict__ w5,
                                                   ushort* __restrict__ Wb,
                                                   ushort* __restrict__ Hsl,
                                                   float* __restrict__ gsum,
                                                   int* __restrict__ deg,
                                                   int* __restrict__ counter) {
    const int tid = blockIdx.x * 256 + threadIdx.x;
    const int NT = gridDim.x * 256;
    if (tid == 0) *counter = 0;
    const float* ptrs[6] = {w0, w1, w2, w3, w4, w5};
    for (int i = tid; i < 6 * DFEAT * DFEAT; i += NT) {
        int m = i >> 14, j = i & 16383;
        Wb[i] = f2bf(ptrs[m][j]);
    }
    for (int i = tid; i < NGRAPH * DFEAT; i += NT) gsum[i] = 0.f;
    for (int i = tid; i < NNODES; i += NT) deg[i] = 0;
    const int n8 = NNODES * DFEAT / 8;
    for (int i = tid; i < n8; i += NT) {
        float4 a = *(const float4*)&x[(size_t)i * 8];
        float4 b = *(const float4*)&x[(size_t)i * 8 + 4];
        ushort8v o;
        o[0] = f2bf(a.x); o[1] = f2bf(a.y); o[2] = f2bf(a.z); o[3] = f2bf(a.w);
        o[4] = f2bf(b.x); o[5] = f2bf(b.y); o[6] = f2bf(b.z); o[7] = f2bf(b.w);
        int n = i >> 4, g = i & 15;
        *(ushort8v*)&Hsl[(size_t)(g >> 1) * SL + (size_t)n * SLF + (g & 1) * 8] = o;
    }
}

// ---------------------------------------------------------------------------
// CSR build, scan-free (proven R10)
// ---------------------------------------------------------------------------
__global__ __launch_bounds__(256) void histo_kernel(const int* __restrict__ rows,
                                                    int* __restrict__ deg) {
    int i = blockIdx.x * 256 + threadIdx.x;
    if (i < NEDGES) atomicAdd(&deg[rows[i]], 1);
}

__global__ __launch_bounds__(256) void alloc_ranges(const int* __restrict__ deg,
                                                    int* __restrict__ offs,
                                                    int* __restrict__ cursor,
                                                    int* __restrict__ counter) {
    __shared__ int red[256];
    __shared__ int baseSh;
    int t = threadIdx.x;
    int i = blockIdx.x * 256 + t;
    int v = (i < NNODES) ? deg[i] : 0;
    red[t] = v;
    __syncthreads();
    int x = v;
    for (int off = 1; off < 256; off <<= 1) {
        int y = (t >= off) ? red[t - off] : 0;
        __syncthreads();
        x += y;
        red[t] = x;
        __syncthreads();
    }
    if (t == 255) baseSh = atomicAdd(counter, x);
    __syncthreads();
    int pos = baseSh + x - v;
    if (i < NNODES) { offs[i] = pos; cursor[i] = pos; }
}

__global__ __launch_bounds__(256) void scatter_edges(const int* __restrict__ rows,
                                                     const int* __restrict__ cols,
                                                     int* __restrict__ cursor,
                                                     int* __restrict__ scol) {
    int i = blockIdx.x * 256 + threadIdx.x;
    if (i < NEDGES) {
        int p = atomicAdd(&cursor[rows[i]], 1);
        scol[p] = cols[i];
    }
}

// ---------------------------------------------------------------------------
// Sliced aggregate: A[s][n][:] = sum_e H[s][scol[e]][:].
// Block b works slice s=b&7; dispatch round-robin puts slice s's blocks on
// XCD s, whose 4 MB L2 holds the whole 3.2 MB slice -> gathers are L2-local.
// Thread = (node, half): two 16 B loads per edge pair of lanes (32 B granule).
// scol loads nontemporal to keep the slice resident.
// ---------------------------------------------------------------------------
__global__ __launch_bounds__(256) void aggregate_sl(const ushort* __restrict__ Hsl,
                                                    const int* __restrict__ offs,
                                                    const int* __restrict__ deg,
                                                    const int* __restrict__ scol,
                                                    ushort* __restrict__ Asl) {
    int s = blockIdx.x & 7;
    int node = (blockIdx.x >> 3) * 128 + (threadIdx.x >> 1);
    int h = threadIdx.x & 1;
    if (node >= NNODES) return;
    const ushort* __restrict__ Hs = Hsl + (size_t)s * SL;
    int beg = offs[node];
    int end = beg + deg[node];
    float a[8] = {};
    int e = beg;
    for (; e + 4 <= end; e += 4) {
        int c0 = __builtin_nontemporal_load(&scol[e]);
        int c1 = __builtin_nontemporal_load(&scol[e + 1]);
        int c2 = __builtin_nontemporal_load(&scol[e + 2]);
        int c3 = __builtin_nontemporal_load(&scol[e + 3]);
        ushort8v v0 = *(const ushort8v*)&Hs[(size_t)c0 * SLF + h * 8];
        ushort8v v1 = *(const ushort8v*)&Hs[(size_t)c1 * SLF + h * 8];
        ushort8v v2 = *(const ushort8v*)&Hs[(size_t)c2 * SLF + h * 8];
        ushort8v v3 = *(const ushort8v*)&Hs[(size_t)c3 * SLF + h * 8];
#pragma unroll
        for (int j = 0; j < 8; ++j)
            a[j] += (bf2f(v0[j]) + bf2f(v1[j])) + (bf2f(v2[j]) + bf2f(v3[j]));
    }
    for (; e < end; ++e) {
        int c0 = __builtin_nontemporal_load(&scol[e]);
        ushort8v v0 = *(const ushort8v*)&Hs[(size_t)c0 * SLF + h * 8];
#pragma unroll
        for (int j = 0; j < 8; ++j) a[j] += bf2f(v0[j]);
    }
    ushort8v o;
#pragma unroll
    for (int j = 0; j < 8; ++j) o[j] = f2bf(a[j]);
    *(ushort8v*)&Asl[(size_t)s * SL + (size_t)node * SLF + h * 8] = o;
}

// ---------------------------------------------------------------------------
// Fused layer GEMM, dual-tile (R13 body, sliced addressing):
// H' = relu(H @ W1^T + A @ W2^T). Fragment k0=ks*32+lhi*8 lives at slice
// (2ks + (lhi>>1)), offset (lhi&1)*8 -> 256 B coalesced per l15 group.
// Per-output math order identical -> results bit-identical.
// ---------------------------------------------------------------------------
__global__ __launch_bounds__(256, 2) void fused_dual_gemm(const ushort* __restrict__ Hsl,
                                                          const ushort* __restrict__ Asl,
                                                          const ushort* __restrict__ W1b,
                                                          const ushort* __restrict__ W2b,
                                                          ushort* __restrict__ Hout) {
    int wid = threadIdx.x >> 6;
    int lane = threadIdx.x & 63;
    int l15 = lane & 15, lhi = lane >> 4;
    int half = wid & 1;
    const int sliceB = lhi >> 1;          // 0..1
    const int rem    = (lhi & 1) * 8;     // 0 or 8

    bf16x8 w1[4][4], w2[4][4];
#pragma unroll
    for (int ot = 0; ot < 4; ++ot)
#pragma unroll
        for (int ks = 0; ks < 4; ++ks) {
            int orow = half * 64 + ot * 16 + l15;
            w1[ot][ks] = *(const bf16x8*)&W1b[orow * DFEAT + ks * 32 + lhi * 8];
            w2[ot][ks] = *(const bf16x8*)&W2b[orow * DFEAT + ks * 32 + lhi * 8];
        }

    int team = blockIdx.x * 2 + (wid >> 1);
    const int nteams = gridDim.x * 2;
    const int ntiles = NNODES / 16;              // 6250 (even)

    for (int t0 = team * 2; t0 < ntiles; t0 += nteams * 2) {
        int n0 = t0 * 16 + l15;
        int n1 = n0 + 16;
        size_t r0 = (size_t)n0 * SLF + rem;
        size_t r1 = (size_t)n1 * SLF + rem;
        bf16x8 hfr0[4], afr0[4], hfr1[4], afr1[4];
#pragma unroll
        for (int ks = 0; ks < 4; ++ks) {
            size_t pl = (size_t)(ks * 2 + sliceB) * SL;
            hfr0[ks] = *(const bf16x8*)&Hsl[pl + r0];
            afr0[ks] = *(const bf16x8*)&Asl[pl + r0];
            hfr1[ks] = *(const bf16x8*)&Hsl[pl + r1];
            afr1[ks] = *(const bf16x8*)&Asl[pl + r1];
        }
#pragma unroll
        for (int ot = 0; ot < 4; ++ot) {
            f32x4 acc0 = {}, acc1 = {};
#pragma unroll
            for (int ks = 0; ks < 4; ++ks) {
                acc0 = __builtin_amdgcn_mfma_f32_16x16x32_bf16(w1[ot][ks], hfr0[ks], acc0, 0, 0, 0);
                acc1 = __builtin_amdgcn_mfma_f32_16x16x32_bf16(w1[ot][ks], hfr1[ks], acc1, 0, 0, 0);
            }
#pragma unroll
            for (int ks = 0; ks < 4; ++ks) {
                acc0 = __builtin_amdgcn_mfma_f32_16x16x32_bf16(w2[ot][ks], afr0[ks], acc0, 0, 0, 0);
                acc1 = __builtin_amdgcn_mfma_f32_16x16x32_bf16(w2[ot][ks], afr1[ks], acc1, 0, 0, 0);
            }
            ushort4 p0, p1;
            p0.x = f2bf(fmaxf(acc0.x, 0.f));
            p0.y = f2bf(fmaxf(acc0.y, 0.f));
            p0.z = f2bf(fmaxf(acc0.z, 0.f));
            p0.w = f2bf(fmaxf(acc0.w, 0.f));
            p1.x = f2bf(fmaxf(acc1.x, 0.f));
            p1.y = f2bf(fmaxf(acc1.y, 0.f));
            p1.z = f2bf(fmaxf(acc1.z, 0.f));
            p1.w = f2bf(fmaxf(acc1.w, 0.f));
            // out-feat o = half*64+ot*16+lhi*4 -> slice half*4+ot, offset lhi*4
            size_t pl = (size_t)(half * 4 + ot) * SL;
            *(ushort4*)&Hout[pl + (size_t)n0 * SLF + lhi * 4] = p0;
            *(ushort4*)&Hout[pl + (size_t)n1 * SLF + lhi * 4] = p1;
        }
    }
}

// ---------------------------------------------------------------------------
// Pooling phase 1 (sliced read): lane owns feats (2l,2l+1) -> slice l>>3,
// uint offset (l&7) within the node's 8-uint slice row.
// ---------------------------------------------------------------------------
__global__ __launch_bounds__(256) void pool_partial(const ushort* __restrict__ Hsl,
                                                    const int* __restrict__ batch,
                                                    float* __restrict__ gsum) {
    int wave = (blockIdx.x * 256 + threadIdx.x) >> 6;
    int lane = threadIdx.x & 63;
    int base = wave * 64;
    if (base >= NNODES) return;
    int end = min(base + 64, NNODES);
    const uint* Hp = (const uint*)Hsl + (size_t)(lane >> 3) * (SL / 2) + (lane & 7);
    float ax = 0.f, ay = 0.f;
    int gprev = batch[base];
    for (int n = base; n < end; ++n) {
        int g = batch[n];
        if (g != gprev) {
            atomicAdd(&gsum[gprev * DFEAT + lane * 2], ax);
            atomicAdd(&gsum[gprev * DFEAT + lane * 2 + 1], ay);
            ax = 0.f; ay = 0.f; gprev = g;
        }
        uint v = Hp[(size_t)n * 8];
        ax += __builtin_bit_cast(float, v << 16);
        ay += __builtin_bit_cast(float, v & 0xffff0000u);
    }
    atomicAdd(&gsum[gprev * DFEAT + lane * 2], ax);
    atomicAdd(&gsum[gprev * DFEAT + lane * 2 + 1], ay);
}

// ---------------------------------------------------------------------------
// Pooling phase 2: divide by count, classify. (proven, unchanged)
// ---------------------------------------------------------------------------
__global__ __launch_bounds__(128) void pool_classify2(const float* __restrict__ gsum,
                                                      const int* __restrict__ batch,
                                                      const float* __restrict__ Wc,
                                                      const float* __restrict__ bc,
                                                      float* __restrict__ out) {
    int g = blockIdx.x;
    int f = threadIdx.x;
    __shared__ int bounds[2];
    if (f < 2) {
        int target = g + f;
        int lo = 0, hi = NNODES;
        while (lo < hi) {
            int mid = (lo + hi) >> 1;
            if (batch[mid] < target) lo = mid + 1; else hi = mid;
        }
        bounds[f] = lo;
    }
    __syncthreads();
    float cnt = (float)(bounds[1] - bounds[0]);
    float pooled = gsum[g * DFEAT + f] / fmaxf(cnt, 1.0f);

    __shared__ float red[128];
    for (int o = 0; o < DOUTC; ++o) {
        red[f] = pooled * Wc[o * DFEAT + f];
        __syncthreads();
        for (int off = 64; off > 0; off >>= 1) {
            if (f < off) red[f] += red[f + off];
            __syncthreads();
        }
        if (f == 0) out[g * DOUTC + o] = red[0] + bc[o];
        __syncthreads();
    }
}

// ---------------------------------------------------------------------------
extern "C" void kernel_launch(void* const* d_in, const int* in_sizes, int n_in,
                              void* d_out, int out_size, void* d_ws, size_t ws_size,
                              hipStream_t stream) {
    const float* x    = (const float*)d_in[0];
    const int*   ei   = (const int*)d_in[1];
    const int*   batch= (const int*)d_in[2];
    const float* Wc   = (const float*)d_in[9];
    const float* bc   = (const float*)d_in[10];
    float* out = (float*)d_out;

    const int* rows = ei;            // edge_index[0] = dst (segment)
    const int* cols = ei + NEDGES;   // edge_index[1] = src (gather)

    // workspace carve-up
    char* ws = (char*)d_ws;
    ushort* Hb = (ushort*)ws;  ws += (size_t)NNODES * DFEAT * sizeof(ushort);   // sliced
    ushort* Hc = (ushort*)ws;  ws += (size_t)NNODES * DFEAT * sizeof(ushort);   // sliced
    ushort* Ab = (ushort*)ws;  ws += (size_t)NNODES * DFEAT * sizeof(ushort);   // sliced
    ushort* Wb = (ushort*)ws;  ws += (size_t)6 * DFEAT * DFEAT * sizeof(ushort);
    float* gsum = (float*)ws;  ws += (size_t)NGRAPH * DFEAT * sizeof(float);
    int* deg    = (int*)ws;    ws += (size_t)NNODES * sizeof(int);
    int* offs   = (int*)ws;    ws += (size_t)NNODES * sizeof(int);
    int* cursor = (int*)ws;    ws += (size_t)NNODES * sizeof(int);
    int* scol   = (int*)ws;    ws += (size_t)NEDGES * sizeof(int);
    int* counter= (int*)ws;    ws += 64;

    // 1) conversions + zero-init
    convert_all<<<784, 256, 0, stream>>>(x,
        (const float*)d_in[3], (const float*)d_in[4], (const float*)d_in[5],
        (const float*)d_in[6], (const float*)d_in[7], (const float*)d_in[8],
        Wb, Hb, gsum, deg, counter);

    // 2) CSR build: histo -> alloc -> scatter
    histo_kernel<<<(NEDGES + 255) / 256, 256, 0, stream>>>(rows, deg);
    alloc_ranges<<<(NNODES + 255) / 256, 256, 0, stream>>>(deg, offs, cursor, counter);
    scatter_edges<<<(NEDGES + 255) / 256, 256, 0, stream>>>(rows, cols, cursor, scol);

    // 3) three GNN layers (sliced layout)
    const int aggGrid  = 8 * ((NNODES + 127) / 128);    // 6256; slice = b&7
    const int gemmGrid = 784;
    const ushort* hcur = Hb;
    ushort* hnext = Hc;
    for (int l = 0; l < 3; ++l) {
        const ushort* w1 = Wb + (size_t)(2 * l) * DFEAT * DFEAT;
        const ushort* w2 = Wb + (size_t)(2 * l + 1) * DFEAT * DFEAT;
        aggregate_sl<<<aggGrid, 256, 0, stream>>>(hcur, offs, deg, scol, Ab);
        fused_dual_gemm<<<gemmGrid, 256, 0, stream>>>(hcur, Ab, w1, w2, hnext);
        const ushort* tmp = hcur; hcur = hnext; hnext = (ushort*)tmp;
    }

    // 4) pooling + classifier
    const int poolWaves = (NNODES + 63) / 64;
    pool_partial<<<(poolWaves * 64 + 255) / 256, 256, 0, stream>>>(hcur, batch, gsum);
    pool_classify2<<<NGRAPH, 128, 0, stream>>>(gsum, batch, Wc, bc, out);
}

// Round 15
// 305.698 us; speedup vs baseline: 1.2373x; 1.2373x over previous
//
#include <hip/hip_runtime.h>

#define NNODES 100000
#define NEDGES 625000
#define DFEAT  128
#define NGRAPH 256
#define DOUTC  10

typedef __attribute__((ext_vector_type(8))) short bf16x8;
typedef __attribute__((ext_vector_type(4))) float f32x4;
typedef __attribute__((ext_vector_type(8))) ushort ushort8v;

__device__ __forceinline__ ushort f2bf(float f) {
    __bf16 b = (__bf16)f;
    return __builtin_bit_cast(ushort, b);
}
__device__ __forceinline__ float bf2f(ushort u) {
    return __builtin_bit_cast(float, (uint)u << 16);
}

// ---------------------------------------------------------------------------
// convert_all: weights->bf16, x->bf16, zero gsum/deg/counter (proven R10)
// ---------------------------------------------------------------------------
__global__ __launch_bounds__(256) void convert_all(const float* __restrict__ x,
                                                   const float* __restrict__ w0,
                                                   const float* __restrict__ w1,
                                                   const float* __restrict__ w2,
                                                   const float* __restrict__ w3,
                                                   const float* __restrict__ w4,
                                                   const float* __restrict__ w5,
                                                   ushort* __restrict__ Wb,
                                                   ushort* __restrict__ Hb,
                                                   float* __restrict__ gsum,
                                                   int* __restrict__ deg,
                                                   int* __restrict__ counter) {
    const int tid = blockIdx.x * 256 + threadIdx.x;
    const int NT = gridDim.x * 256;
    if (tid == 0) *counter = 0;
    const float* ptrs[6] = {w0, w1, w2, w3, w4, w5};
    for (int i = tid; i < 6 * DFEAT * DFEAT; i += NT) {
        int m = i >> 14, j = i & 16383;
        Wb[i] = f2bf(ptrs[m][j]);
    }
    for (int i = tid; i < NGRAPH * DFEAT; i += NT) gsum[i] = 0.f;
    for (int i = tid; i < NNODES; i += NT) deg[i] = 0;
    const int n8 = NNODES * DFEAT / 8;
    for (int i = tid; i < n8; i += NT) {
        float4 a = *(const float4*)&x[(size_t)i * 8];
        float4 b = *(const float4*)&x[(size_t)i * 8 + 4];
        ushort8v o;
        o[0] = f2bf(a.x); o[1] = f2bf(a.y); o[2] = f2bf(a.z); o[3] = f2bf(a.w);
        o[4] = f2bf(b.x); o[5] = f2bf(b.y); o[6] = f2bf(b.z); o[7] = f2bf(b.w);
        *(ushort8v*)&Hb[(size_t)i * 8] = o;
    }
}

// ---------------------------------------------------------------------------
// CSR build, scan-free (proven R10)
// ---------------------------------------------------------------------------
__global__ __launch_bounds__(256) void histo_kernel(const int* __restrict__ rows,
                                                    int* __restrict__ deg) {
    int i = blockIdx.x * 256 + threadIdx.x;
    if (i < NEDGES) atomicAdd(&deg[rows[i]], 1);
}

__global__ __launch_bounds__(256) void alloc_ranges(const int* __restrict__ deg,
                                                    int* __restrict__ offs,
                                                    int* __restrict__ cursor,
                                                    int* __restrict__ counter) {
    __shared__ int red[256];
    __shared__ int baseSh;
    int t = threadIdx.x;
    int i = blockIdx.x * 256 + t;
    int v = (i < NNODES) ? deg[i] : 0;
    red[t] = v;
    __syncthreads();
    int x = v;
    for (int off = 1; off < 256; off <<= 1) {
        int y = (t >= off) ? red[t - off] : 0;
        __syncthreads();
        x += y;
        red[t] = x;
        __syncthreads();
    }
    if (t == 255) baseSh = atomicAdd(counter, x);
    __syncthreads();
    int pos = baseSh + x - v;
    if (i < NNODES) { offs[i] = pos; cursor[i] = pos; }
}

__global__ __launch_bounds__(256) void scatter_edges(const int* __restrict__ rows,
                                                     const int* __restrict__ cols,
                                                     int* __restrict__ cursor,
                                                     int* __restrict__ scol) {
    int i = blockIdx.x * 256 + threadIdx.x;
    if (i < NEDGES) {
        int p = atomicAdd(&cursor[rows[i]], 1);
        scol[p] = cols[i];
    }
}

// ---------------------------------------------------------------------------
// Aggregate in H-space (R13 body, byte-identical): 16-lane group per node,
// 4 edge-rows in flight; 256 B coalesced row reads (proven optimal pattern).
// ---------------------------------------------------------------------------
__global__ __launch_bounds__(256) void aggregate_g16(const ushort* __restrict__ Hb,
                                                     const int* __restrict__ offs,
                                                     const int* __restrict__ deg,
                                                     const int* __restrict__ scol,
                                                     ushort* __restrict__ Ab) {
    int node = blockIdx.x * 16 + (threadIdx.x >> 4);
    int l = threadIdx.x & 15;
    if (node >= NNODES) return;
    int beg = offs[node];
    int end = beg + deg[node];
    float a[8] = {};
    int e = beg;
    for (; e + 4 <= end; e += 4) {
        int c0 = scol[e];
        int c1 = scol[e + 1];
        int c2 = scol[e + 2];
        int c3 = scol[e + 3];
        ushort8v v0 = *(const ushort8v*)&Hb[(size_t)c0 * DFEAT + l * 8];
        ushort8v v1 = *(const ushort8v*)&Hb[(size_t)c1 * DFEAT + l * 8];
        ushort8v v2 = *(const ushort8v*)&Hb[(size_t)c2 * DFEAT + l * 8];
        ushort8v v3 = *(const ushort8v*)&Hb[(size_t)c3 * DFEAT + l * 8];
#pragma unroll
        for (int j = 0; j < 8; ++j)
            a[j] += (bf2f(v0[j]) + bf2f(v1[j])) + (bf2f(v2[j]) + bf2f(v3[j]));
    }
    for (; e < end; ++e) {
        int c0 = scol[e];
        ushort8v v0 = *(const ushort8v*)&Hb[(size_t)c0 * DFEAT + l * 8];
#pragma unroll
        for (int j = 0; j < 8; ++j) a[j] += bf2f(v0[j]);
    }
    ushort8v o;
#pragma unroll
    for (int j = 0; j < 8; ++j) o[j] = f2bf(a[j]);
    *(ushort8v*)&Ab[(size_t)node * DFEAT + l * 8] = o;
}

// ---------------------------------------------------------------------------
// Fused layer GEMM, quarter-split + reg-pinned weights:
// H' = relu(H @ W1^T + A @ W2^T). Wave owns 32 out-features (64 VGPR of
// weights); __launch_bounds__(256,4) -> 16 waves/CU (2x R10's occupancy).
// The empty asm pins each weight fragment's value in VGPRs: the asm def is
// opaque, so the compiler CANNOT rematerialize the loads inside the tile
// loop (R11's VGPR=48 remat bug). Per-output math order identical to R10.
// ---------------------------------------------------------------------------
__global__ __launch_bounds__(256, 4) void fused_dual_gemm_q(const ushort* __restrict__ Hin,
                                                            const ushort* __restrict__ Ab,
                                                            const ushort* __restrict__ W1b,
                                                            const ushort* __restrict__ W2b,
                                                            ushort* __restrict__ Hout) {
    int wid = threadIdx.x >> 6;              // out-quarter 0..3
    int lane = threadIdx.x & 63;
    int l15 = lane & 15, lhi = lane >> 4;

    bf16x8 w1[2][4], w2[2][4];
#pragma unroll
    for (int ot = 0; ot < 2; ++ot)
#pragma unroll
        for (int ks = 0; ks < 4; ++ks) {
            int orow = wid * 32 + ot * 16 + l15;
            w1[ot][ks] = *(const bf16x8*)&W1b[orow * DFEAT + ks * 32 + lhi * 8];
            w2[ot][ks] = *(const bf16x8*)&W2b[orow * DFEAT + ks * 32 + lhi * 8];
        }
    // pin weight fragments in registers (defeat rematerialization)
#pragma unroll
    for (int ot = 0; ot < 2; ++ot)
#pragma unroll
        for (int ks = 0; ks < 4; ++ks) {
            asm volatile("" : "+v"(w1[ot][ks]));
            asm volatile("" : "+v"(w2[ot][ks]));
        }

    const int ntiles = NNODES / 16;              // 6250
    for (int t = blockIdx.x; t < ntiles; t += gridDim.x) {
        size_t rowOff = (size_t)(t * 16 + l15) * DFEAT;
        bf16x8 hfr[4], afr[4];
#pragma unroll
        for (int ks = 0; ks < 4; ++ks) {
            hfr[ks] = *(const bf16x8*)&Hin[rowOff + ks * 32 + lhi * 8];
            afr[ks] = *(const bf16x8*)&Ab[rowOff + ks * 32 + lhi * 8];
        }
#pragma unroll
        for (int ot = 0; ot < 2; ++ot) {
            f32x4 acc = {};
#pragma unroll
            for (int ks = 0; ks < 4; ++ks)
                acc = __builtin_amdgcn_mfma_f32_16x16x32_bf16(w1[ot][ks], hfr[ks], acc, 0, 0, 0);
#pragma unroll
            for (int ks = 0; ks < 4; ++ks)
                acc = __builtin_amdgcn_mfma_f32_16x16x32_bf16(w2[ot][ks], afr[ks], acc, 0, 0, 0);
            ushort4 p;
            p.x = f2bf(fmaxf(acc.x, 0.f));
            p.y = f2bf(fmaxf(acc.y, 0.f));
            p.z = f2bf(fmaxf(acc.z, 0.f));
            p.w = f2bf(fmaxf(acc.w, 0.f));
            *(ushort4*)&Hout[rowOff + wid * 32 + ot * 16 + lhi * 4] = p;
        }
    }
}

// ---------------------------------------------------------------------------
// Pooling phase 1: per-graph feature sums (proven R10)
// ---------------------------------------------------------------------------
__global__ __launch_bounds__(256) void pool_partial(const ushort* __restrict__ Hb,
                                                    const int* __restrict__ batch,
                                                    float* __restrict__ gsum) {
    int wave = (blockIdx.x * 256 + threadIdx.x) >> 6;
    int lane = threadIdx.x & 63;
    int base = wave * 64;
    if (base >= NNODES) return;
    int end = min(base + 64, NNODES);
    const uint* Hp = (const uint*)Hb + lane;
    float ax = 0.f, ay = 0.f;
    int gprev = batch[base];
    for (int n = base; n < end; ++n) {
        int g = batch[n];
        if (g != gprev) {
            atomicAdd(&gsum[gprev * DFEAT + lane * 2], ax);
            atomicAdd(&gsum[gprev * DFEAT + lane * 2 + 1], ay);
            ax = 0.f; ay = 0.f; gprev = g;
        }
        uint v = Hp[(size_t)n * 64];
        ax += __builtin_bit_cast(float, v << 16);
        ay += __builtin_bit_cast(float, v & 0xffff0000u);
    }
    atomicAdd(&gsum[gprev * DFEAT + lane * 2], ax);
    atomicAdd(&gsum[gprev * DFEAT + lane * 2 + 1], ay);
}

// ---------------------------------------------------------------------------
// Pooling phase 2: divide by count, classify. (proven R10)
// ---------------------------------------------------------------------------
__global__ __launch_bounds__(128) void pool_classify2(const float* __restrict__ gsum,
                                                      const int* __restrict__ batch,
                                                      const float* __restrict__ Wc,
                                                      const float* __restrict__ bc,
                                                      float* __restrict__ out) {
    int g = blockIdx.x;
    int f = threadIdx.x;
    __shared__ int bounds[2];
    if (f < 2) {
        int target = g + f;
        int lo = 0, hi = NNODES;
        while (lo < hi) {
            int mid = (lo + hi) >> 1;
            if (batch[mid] < target) lo = mid + 1; else hi = mid;
        }
        bounds[f] = lo;
    }
    __syncthreads();
    float cnt = (float)(bounds[1] - bounds[0]);
    float pooled = gsum[g * DFEAT + f] / fmaxf(cnt, 1.0f);

    __shared__ float red[128];
    for (int o = 0; o < DOUTC; ++o) {
        red[f] = pooled * Wc[o * DFEAT + f];
        __syncthreads();
        for (int off = 64; off > 0; off >>= 1) {
            if (f < off) red[f] += red[f + off];
            __syncthreads();
        }
        if (f == 0) out[g * DOUTC + o] = red[0] + bc[o];
        __syncthreads();
    }
}

// ---------------------------------------------------------------------------
extern "C" void kernel_launch(void* const* d_in, const int* in_sizes, int n_in,
                              void* d_out, int out_size, void* d_ws, size_t ws_size,
                              hipStream_t stream) {
    const float* x    = (const float*)d_in[0];
    const int*   ei   = (const int*)d_in[1];
    const int*   batch= (const int*)d_in[2];
    const float* Wc   = (const float*)d_in[9];
    const float* bc   = (const float*)d_in[10];
    float* out = (float*)d_out;

    const int* rows = ei;            // edge_index[0] = dst (segment)
    const int* cols = ei + NEDGES;   // edge_index[1] = src (gather)

    // workspace carve-up
    char* ws = (char*)d_ws;
    ushort* Hb = (ushort*)ws;  ws += (size_t)NNODES * DFEAT * sizeof(ushort);
    ushort* Hc = (ushort*)ws;  ws += (size_t)NNODES * DFEAT * sizeof(ushort);
    ushort* Ab = (ushort*)ws;  ws += (size_t)NNODES * DFEAT * sizeof(ushort);
    ushort* Wb = (ushort*)ws;  ws += (size_t)6 * DFEAT * DFEAT * sizeof(ushort);
    float* gsum = (float*)ws;  ws += (size_t)NGRAPH * DFEAT * sizeof(float);
    int* deg    = (int*)ws;    ws += (size_t)NNODES * sizeof(int);
    int* offs   = (int*)ws;    ws += (size_t)NNODES * sizeof(int);
    int* cursor = (int*)ws;    ws += (size_t)NNODES * sizeof(int);
    int* scol   = (int*)ws;    ws += (size_t)NEDGES * sizeof(int);
    int* counter= (int*)ws;    ws += 64;

    // 1) conversions + zero-init
    convert_all<<<784, 256, 0, stream>>>(x,
        (const float*)d_in[3], (const float*)d_in[4], (const float*)d_in[5],
        (const float*)d_in[6], (const float*)d_in[7], (const float*)d_in[8],
        Wb, Hb, gsum, deg, counter);

    // 2) CSR build: histo -> alloc -> scatter
    histo_kernel<<<(NEDGES + 255) / 256, 256, 0, stream>>>(rows, deg);
    alloc_ranges<<<(NNODES + 255) / 256, 256, 0, stream>>>(deg, offs, cursor, counter);
    scatter_edges<<<(NEDGES + 255) / 256, 256, 0, stream>>>(rows, cols, cursor, scol);

    // 3) three GNN layers
    const int aggGrid  = (NNODES + 15) / 16;
    const int gemmGrid = 1024;               // 4 blocks/CU, ~6 tiles each
    const ushort* hcur = Hb;
    ushort* hnext = Hc;
    for (int l = 0; l < 3; ++l) {
        const ushort* w1 = Wb + (size_t)(2 * l) * DFEAT * DFEAT;
        const ushort* w2 = Wb + (size_t)(2 * l + 1) * DFEAT * DFEAT;
        aggregate_g16<<<aggGrid, 256, 0, stream>>>(hcur, offs, deg, scol, Ab);
        fused_dual_gemm_q<<<gemmGrid, 256, 0, stream>>>(hcur, Ab, w1, w2, hnext);
        const ushort* tmp = hcur; hcur = hnext; hnext = (ushort*)tmp;
    }

    // 4) pooling + classifier
    const int poolWaves = (NNODES + 63) / 64;
    pool_partial<<<(poolWaves * 64 + 255) / 256, 256, 0, stream>>>(hcur, batch, gsum);
    pool_classify2<<<NGRAPH, 128, 0, stream>>>(gsum, batch, Wc, bc, out);
}